// Round 10
// baseline (220.977 us; speedup 1.0000x reference)
//
#include <hip/hip_runtime.h>

constexpr int N_NODES = 50000;
constexpr int N_EDGES = 800000;
constexpr int D = 64;
constexpr int NB = (N_NODES + 63) / 64;      // 782 buckets of 64 dst nodes
constexpr int BUCKET_CAP = 1280;             // mean load 1023 -> 8-sigma pad

typedef __attribute__((ext_vector_type(8))) short short8;
typedef __attribute__((ext_vector_type(4))) float f32x4;

static __device__ inline unsigned short f2bf(float f) {
    unsigned u = __float_as_uint(f);
    unsigned r = (u + 0x7FFFu + ((u >> 16) & 1u)) >> 16;   // RNE
    return (unsigned short)r;
}
static __device__ inline unsigned pack2(float lo, float hi) {
    return (unsigned)f2bf(lo) | ((unsigned)f2bf(hi) << 16);
}
static __device__ inline float bf2f(unsigned short b) {
    return __uint_as_float((unsigned)b << 16);
}

// ---------------------------------------------------------------------------
// INSTRUMENTATION (this round only): ~50us wall pad so kernels surface in
// top-5 above the 47us ws-poison fills. shown_dur - 50us = true dur.
// s_memrealtime ticks at ~100 MHz -> 5000 ticks = 50us. Same work every call.
// ---------------------------------------------------------------------------
static __device__ inline void sleep_pad() {
    unsigned long long t0 = __builtin_amdgcn_s_memrealtime();
    while (__builtin_amdgcn_s_memrealtime() - t0 < 5000ULL)
        __builtin_amdgcn_s_sleep(32);
}

// ---------------------------------------------------------------------------
// 1) merged prep + binning. 256 blocks x 512.
//    - convert x fp32->bf16 (striped across all blocks; overlaps binning)
//    - block 0 packs W to bf16
//    - two-pass binning into padded buckets; cursor pre-zeroed by memset,
//      holds per-bucket COUNT; bucket b's data at bucket_data[b*CAP ...]
// ---------------------------------------------------------------------------
constexpr int BIN_BLOCKS = 256;
constexpr int EDGES_PER_BIN_BLOCK = (N_EDGES + BIN_BLOCKS - 1) / BIN_BLOCKS;  // 3125

__global__ __launch_bounds__(512) void k_bin_place(
    const float* __restrict__ x, unsigned short* __restrict__ xb,
    const float* __restrict__ W_msg, const float* __restrict__ W_self,
    unsigned short* __restrict__ B_packed,
    const int* __restrict__ edge_index,
    unsigned* __restrict__ g_cursor, unsigned* __restrict__ bucket_data)
{
    __shared__ unsigned lcount[NB];
    __shared__ unsigned lbase[NB];

    int tid = threadIdx.x;

    // LDS init (no sync needed yet)
    for (int b = tid; b < NB; b += 512) lcount[b] = 0u;

    // x convert, striped across the whole grid (BW-bound, overlaps atomics)
    int gid = blockIdx.x * 512 + tid;
    for (int t = gid; t < N_NODES * D / 4; t += BIN_BLOCKS * 512) {
        float4 v = ((const float4*)x)[t];
        uint2 p;
        p.x = pack2(v.x, v.y);
        p.y = pack2(v.z, v.w);
        ((uint2*)xb)[t] = p;
    }
    if (blockIdx.x == 0) {
        for (int idx = tid; idx < 64 * 128; idx += 512) {
            int n = idx >> 7;
            int k = idx & 127;
            float v = (k < 64) ? W_self[n * 64 + k] : W_msg[n * 64 + (k - 64)];
            B_packed[idx] = f2bf(v);
        }
    }

    int e0 = blockIdx.x * EDGES_PER_BIN_BLOCK;
    int e1 = min(e0 + EDGES_PER_BIN_BLOCK, N_EDGES);
    __syncthreads();

    for (int e = e0 + tid; e < e1; e += 512)
        atomicAdd(&lcount[edge_index[N_EDGES + e] >> 6], 1u);
    __syncthreads();

    for (int b = tid; b < NB; b += 512) {
        unsigned c = lcount[b];
        lbase[b] = c ? ((unsigned)b * BUCKET_CAP + atomicAdd(&g_cursor[b], c)) : 0u;
    }
    __syncthreads();
    for (int b = tid; b < NB; b += 512) lcount[b] = 0u;
    __syncthreads();

    for (int e = e0 + tid; e < e1; e += 512) {
        int dst = edge_index[N_EDGES + e];
        int src = edge_index[e];
        int b = dst >> 6;
        unsigned off = atomicAdd(&lcount[b], 1u);
        bucket_data[lbase[b] + off] = (unsigned)src | ((unsigned)(dst & 63) << 16);
    }

    if (tid == 0) sleep_pad();   // INSTRUMENTATION
}

// ---------------------------------------------------------------------------
// 2) fused: LDS counting-sort by dst -> per-node sequential gather
//    (quarter-wave per edge, fp32 reg accumulation) -> bf16 MFMA GEMM.
//    (round-9 logic; cursor now holds COUNT, not absolute end)
// ---------------------------------------------------------------------------
constexpr int A_STRIDE = 136;   // u16 units; 272B row stride

__global__ __launch_bounds__(512) void k_fused(
    const unsigned short* __restrict__ x_bf16,
    const unsigned short* __restrict__ B_packed,
    const float* __restrict__ b_msg, const float* __restrict__ b_self,
    const unsigned* __restrict__ cursor,
    const unsigned* __restrict__ bucket_data,
    float* __restrict__ out)
{
    __shared__ __align__(16) unsigned short A_sh[64 * A_STRIDE];   // 17408 B
    __shared__ __align__(16) unsigned short B_sh[64 * A_STRIDE];   // 17408 B
    __shared__ unsigned short sorted_sh[BUCKET_CAP];               // 2560 B
    __shared__ unsigned cnt_sh[64];
    __shared__ unsigned off_sh[64];
    __shared__ unsigned woff_sh[64];

    int tid  = threadIdx.x;
    int w    = tid >> 6;       // wave 0..7
    int lane = tid & 63;
    int r0   = blockIdx.x * 64;

    unsigned start = (unsigned)blockIdx.x * BUCKET_CAP;
    unsigned end   = start + cursor[blockIdx.x];     // cursor = count

    if (tid < 64) cnt_sh[tid] = 0u;
    for (int idx = tid; idx < 64 * 16; idx += 512) {
        int row = idx >> 4;
        int c   = idx & 15;
        int g   = r0 + row;
        uint2 v = make_uint2(0u, 0u);
        if (g < N_NODES) v = *(const uint2*)&x_bf16[g * D + c * 4];
        *(uint2*)&A_sh[row * A_STRIDE + c * 4] = v;
    }
    for (int idx = tid; idx < 64 * 32; idx += 512) {
        int n = idx >> 5;
        int c = idx & 31;
        uint2 v = *(const uint2*)&B_packed[n * 128 + c * 4];
        *(uint2*)&B_sh[n * A_STRIDE + c * 4] = v;
    }
    __syncthreads();

    for (unsigned i = start + tid; i < end; i += 512u)
        atomicAdd(&cnt_sh[bucket_data[i] >> 16], 1u);
    __syncthreads();

    if (tid < 64) {
        unsigned c = cnt_sh[tid];
        unsigned xsum = c;
        #pragma unroll
        for (int s = 1; s < 64; s <<= 1) {
            unsigned v = (unsigned)__shfl_up((int)xsum, s);
            if (lane >= s) xsum += v;
        }
        off_sh[tid]  = xsum - c;
        woff_sh[tid] = xsum - c;
    }
    __syncthreads();

    for (unsigned i = start + tid; i < end; i += 512u) {
        unsigned e = bucket_data[i];
        unsigned slot = atomicAdd(&woff_sh[e >> 16], 1u);
        sorted_sh[slot] = (unsigned short)(e & 0xFFFFu);
    }
    __syncthreads();

    int Q = lane >> 4;
    int f = lane & 15;

    for (int i = 0; i < 8; ++i) {
        int lrow = w * 8 + i;
        unsigned s0 = off_sh[lrow];
        unsigned dc = cnt_sh[lrow];
        unsigned e_end = s0 + dc;

        float a0 = 0.f, a1 = 0.f, a2 = 0.f, a3 = 0.f;
        for (unsigned b = s0; b < e_end; b += 8u) {
            unsigned i0 = b + (unsigned)Q;
            unsigned i1 = b + 4u + (unsigned)Q;
            unsigned src0 = (i0 < e_end) ? (unsigned)sorted_sh[i0] : 0u;
            unsigned src1 = (i1 < e_end) ? (unsigned)sorted_sh[i1] : 0u;
            ushort4 rv0 = *(const ushort4*)&x_bf16[(src0 << 6) + 4u * (unsigned)f];
            ushort4 rv1 = *(const ushort4*)&x_bf16[(src1 << 6) + 4u * (unsigned)f];
            if (i0 < e_end) {
                a0 += bf2f(rv0.x); a1 += bf2f(rv0.y);
                a2 += bf2f(rv0.z); a3 += bf2f(rv0.w);
            }
            if (i1 < e_end) {
                a0 += bf2f(rv1.x); a1 += bf2f(rv1.y);
                a2 += bf2f(rv1.z); a3 += bf2f(rv1.w);
            }
        }
        a0 += __shfl_xor(a0, 16); a1 += __shfl_xor(a1, 16);
        a2 += __shfl_xor(a2, 16); a3 += __shfl_xor(a3, 16);
        a0 += __shfl_xor(a0, 32); a1 += __shfl_xor(a1, 32);
        a2 += __shfl_xor(a2, 32); a3 += __shfl_xor(a3, 32);

        if (Q == 0) {
            float inv = dc ? 1.0f / (float)dc : 0.0f;
            uint2 p;
            p.x = pack2(a0 * inv, a1 * inv);
            p.y = pack2(a2 * inv, a3 * inv);
            *(uint2*)&A_sh[lrow * A_STRIDE + 64 + 4 * f] = p;
        }
    }
    __syncthreads();

    int wm   = w & 3;
    int ng   = (w >> 2) * 2;
    int quad = lane >> 4;
    int l15  = lane & 15;

    f32x4 accr[2] = {{0.f,0.f,0.f,0.f},{0.f,0.f,0.f,0.f}};

    #pragma unroll
    for (int k0 = 0; k0 < 128; k0 += 32) {
        short8 a = *(const short8*)&A_sh[(16 * wm + l15) * A_STRIDE + k0 + quad * 8];
        #pragma unroll
        for (int t = 0; t < 2; ++t) {
            short8 b = *(const short8*)&B_sh[(16 * (ng + t) + l15) * A_STRIDE + k0 + quad * 8];
            accr[t] = __builtin_amdgcn_mfma_f32_16x16x32_bf16(a, b, accr[t], 0, 0, 0);
        }
    }

    #pragma unroll
    for (int t = 0; t < 2; ++t) {
        int col = (ng + t) * 16 + l15;
        float bs = b_self[col];
        float bm = b_msg[col];
        #pragma unroll
        for (int r = 0; r < 4; ++r) {
            int lrow = 16 * wm + quad * 4 + r;
            int grow = r0 + lrow;
            if (grow < N_NODES) {
                float vv = accr[t][r] + bs + (cnt_sh[lrow] > 0u ? bm : 0.0f);
                out[grow * D + col] = vv;
            }
        }
    }

    if (tid == 0) sleep_pad();   // INSTRUMENTATION
}

// ---------------------------------------------------------------------------
extern "C" void kernel_launch(void* const* d_in, const int* in_sizes, int n_in,
                              void* d_out, int out_size, void* d_ws, size_t ws_size,
                              hipStream_t stream) {
    const float* x      = (const float*)d_in[0];
    const int*   edges  = (const int*)  d_in[1];
    const float* W_msg  = (const float*)d_in[2];
    const float* b_msg  = (const float*)d_in[3];
    const float* W_self = (const float*)d_in[4];
    const float* b_self = (const float*)d_in[5];
    float*       out    = (float*)d_out;

    // workspace layout (bytes), total ~10.5 MB
    char* ws = (char*)d_ws;
    unsigned*       cursor      = (unsigned*)(ws + 0);             // NB u32 (counts)
    unsigned short* B_packed    = (unsigned short*)(ws + 4096);    // 16 KB
    unsigned*       bucket_data = (unsigned*)(ws + 20480);         // ~4 MB
    unsigned short* x_bf16      = (unsigned short*)(ws + 4030464); // 6.4 MB

    hipMemsetAsync(cursor, 0, NB * sizeof(unsigned), stream);      // 3 KB

    k_bin_place<<<BIN_BLOCKS, 512, 0, stream>>>(x, x_bf16, W_msg, W_self,
                                                B_packed, edges, cursor, bucket_data);
    k_fused<<<NB, 512, 0, stream>>>(x_bf16, B_packed, b_msg, b_self,
                                    cursor, bucket_data, out);
}

// Round 11
// 116.396 us; speedup vs baseline: 1.8985x; 1.8985x over previous
//
#include <hip/hip_runtime.h>

constexpr int N_NODES = 50000;
constexpr int N_EDGES = 800000;
constexpr int D = 64;
constexpr int NB = (N_NODES + 63) / 64;      // 782 buckets of 64 dst nodes
constexpr int BUCKET_CAP = 1280;             // mean load 1023 -> 8-sigma pad

typedef __attribute__((ext_vector_type(8))) short short8;
typedef __attribute__((ext_vector_type(4))) float f32x4;

static __device__ inline unsigned short f2bf(float f) {
    unsigned u = __float_as_uint(f);
    unsigned r = (u + 0x7FFFu + ((u >> 16) & 1u)) >> 16;   // RNE
    return (unsigned short)r;
}
static __device__ inline unsigned pack2(float lo, float hi) {
    return (unsigned)f2bf(lo) | ((unsigned)f2bf(hi) << 16);
}
static __device__ inline float bf2f(unsigned short b) {
    return __uint_as_float((unsigned)b << 16);
}

// ---------------------------------------------------------------------------
// 1) merged prep + binning. 256 blocks x 512 threads, 3125 edges/block.
//    Pass 1 reads the edge list ONCE, caching entries in LDS (src,dst pack
//    into 32 bits: both < 65536) while counting buckets. Pass 2 scatters
//    from LDS. x convert + W pack striped across blocks (BW work overlaps
//    the atomic-latency binning).
// ---------------------------------------------------------------------------
constexpr int BIN_BLOCKS = 256;
constexpr int EDGES_PER_BIN_BLOCK = (N_EDGES + BIN_BLOCKS - 1) / BIN_BLOCKS;  // 3125

__global__ __launch_bounds__(512) void k_bin_place(
    const float* __restrict__ x, unsigned short* __restrict__ xb,
    const float* __restrict__ W_msg, const float* __restrict__ W_self,
    unsigned short* __restrict__ B_packed,
    const int* __restrict__ edge_index,
    unsigned* __restrict__ g_cursor, unsigned* __restrict__ bucket_data)
{
    __shared__ unsigned ent_sh[EDGES_PER_BIN_BLOCK];   // 12.5 KB
    __shared__ unsigned lcount[NB];
    __shared__ unsigned lbase[NB];

    int tid = threadIdx.x;

    for (int b = tid; b < NB; b += 512) lcount[b] = 0u;

    // x convert, striped across the whole grid
    int gid = blockIdx.x * 512 + tid;
    for (int t = gid; t < N_NODES * D / 4; t += BIN_BLOCKS * 512) {
        float4 v = ((const float4*)x)[t];
        uint2 p;
        p.x = pack2(v.x, v.y);
        p.y = pack2(v.z, v.w);
        ((uint2*)xb)[t] = p;
    }
    if (blockIdx.x == 0) {
        for (int idx = tid; idx < 64 * 128; idx += 512) {
            int n = idx >> 7;
            int k = idx & 127;
            float v = (k < 64) ? W_self[n * 64 + k] : W_msg[n * 64 + (k - 64)];
            B_packed[idx] = f2bf(v);
        }
    }

    int e0 = blockIdx.x * EDGES_PER_BIN_BLOCK;
    int e1 = min(e0 + EDGES_PER_BIN_BLOCK, N_EDGES);
    int ne = e1 - e0;
    __syncthreads();

    // pass 1: read global once, cache in LDS, count buckets
    for (int e = e0 + tid; e < e1; e += 512) {
        int dst = edge_index[N_EDGES + e];
        int src = edge_index[e];
        ent_sh[e - e0] = ((unsigned)src << 16) | (unsigned)dst;
        atomicAdd(&lcount[dst >> 6], 1u);
    }
    __syncthreads();

    // reserve contiguous ranges (one global atomic per non-empty bucket)
    for (int b = tid; b < NB; b += 512) {
        unsigned c = lcount[b];
        lbase[b] = c ? ((unsigned)b * BUCKET_CAP + atomicAdd(&g_cursor[b], c)) : 0u;
    }
    __syncthreads();
    for (int b = tid; b < NB; b += 512) lcount[b] = 0u;
    __syncthreads();

    // pass 2: scatter from LDS
    for (int i = tid; i < ne; i += 512) {
        unsigned ent = ent_sh[i];
        unsigned dst = ent & 0xFFFFu;
        unsigned b   = dst >> 6;
        unsigned off = atomicAdd(&lcount[b], 1u);
        bucket_data[lbase[b] + off] = (ent >> 16) | ((dst & 63u) << 16);
    }
}

// ---------------------------------------------------------------------------
// 2) fused: LDS counting-sort by dst -> per-node sequential gather
//    (quarter-wave per edge, 4 loads in flight) -> bf16 MFMA GEMM.
// ---------------------------------------------------------------------------
constexpr int A_STRIDE = 136;   // u16 units; 272B row stride (16B-divisible)

__global__ __launch_bounds__(512) void k_fused(
    const unsigned short* __restrict__ x_bf16,
    const unsigned short* __restrict__ B_packed,
    const float* __restrict__ b_msg, const float* __restrict__ b_self,
    const unsigned* __restrict__ cursor,
    const unsigned* __restrict__ bucket_data,
    float* __restrict__ out)
{
    __shared__ __align__(16) unsigned short A_sh[64 * A_STRIDE];   // 17408 B
    __shared__ __align__(16) unsigned short B_sh[64 * A_STRIDE];   // 17408 B
    __shared__ unsigned short sorted_sh[BUCKET_CAP];               // 2560 B
    __shared__ unsigned cnt_sh[64];
    __shared__ unsigned off_sh[64];
    __shared__ unsigned woff_sh[64];

    int tid  = threadIdx.x;
    int w    = tid >> 6;       // wave 0..7
    int lane = tid & 63;
    int r0   = blockIdx.x * 64;

    unsigned start = (unsigned)blockIdx.x * BUCKET_CAP;
    unsigned end   = start + cursor[blockIdx.x];     // cursor = count

    if (tid < 64) cnt_sh[tid] = 0u;
    // stage A x-rows (k<64): 8x 16B chunks per row
    for (int idx = tid; idx < 64 * 8; idx += 512) {
        int row = idx >> 3;
        int c   = idx & 7;
        int g   = r0 + row;
        uint4 v = make_uint4(0u, 0u, 0u, 0u);
        if (g < N_NODES) v = *(const uint4*)&x_bf16[g * D + c * 8];
        *(uint4*)&A_sh[row * A_STRIDE + c * 8] = v;
    }
    // stage B: 16x 16B chunks per row
    for (int idx = tid; idx < 64 * 16; idx += 512) {
        int n = idx >> 4;
        int c = idx & 15;
        uint4 v = *(const uint4*)&B_packed[n * 128 + c * 8];
        *(uint4*)&B_sh[n * A_STRIDE + c * 8] = v;
    }
    __syncthreads();

    // counting sort by dst-low: count
    for (unsigned i = start + tid; i < end; i += 512u)
        atomicAdd(&cnt_sh[bucket_data[i] >> 16], 1u);
    __syncthreads();

    if (tid < 64) {
        unsigned c = cnt_sh[tid];
        unsigned xsum = c;
        #pragma unroll
        for (int s = 1; s < 64; s <<= 1) {
            unsigned v = (unsigned)__shfl_up((int)xsum, s);
            if (lane >= s) xsum += v;
        }
        off_sh[tid]  = xsum - c;
        woff_sh[tid] = xsum - c;
    }
    __syncthreads();

    for (unsigned i = start + tid; i < end; i += 512u) {
        unsigned e = bucket_data[i];
        unsigned slot = atomicAdd(&woff_sh[e >> 16], 1u);
        sorted_sh[slot] = (unsigned short)(e & 0xFFFFu);
    }
    __syncthreads();

    // gather: wave w -> nodes w*8..w*8+7; quarter-wave per edge, 4 loads in flight
    int Q = lane >> 4;
    int f = lane & 15;

    for (int i = 0; i < 8; ++i) {
        int lrow = w * 8 + i;
        unsigned s0 = off_sh[lrow];
        unsigned dc = cnt_sh[lrow];
        unsigned e_end = s0 + dc;

        float a0 = 0.f, a1 = 0.f, a2 = 0.f, a3 = 0.f;
        for (unsigned b = s0; b < e_end; b += 16u) {
            unsigned ii[4];
            ushort4  rv[4];
            #pragma unroll
            for (int u = 0; u < 4; ++u) {
                ii[u] = b + 4u * u + (unsigned)Q;
                unsigned src = (ii[u] < e_end) ? (unsigned)sorted_sh[ii[u]] : 0u;
                rv[u] = *(const ushort4*)&x_bf16[(src << 6) + 4u * (unsigned)f];
            }
            #pragma unroll
            for (int u = 0; u < 4; ++u) {
                if (ii[u] < e_end) {
                    a0 += bf2f(rv[u].x); a1 += bf2f(rv[u].y);
                    a2 += bf2f(rv[u].z); a3 += bf2f(rv[u].w);
                }
            }
        }
        a0 += __shfl_xor(a0, 16); a1 += __shfl_xor(a1, 16);
        a2 += __shfl_xor(a2, 16); a3 += __shfl_xor(a3, 16);
        a0 += __shfl_xor(a0, 32); a1 += __shfl_xor(a1, 32);
        a2 += __shfl_xor(a2, 32); a3 += __shfl_xor(a3, 32);

        if (Q == 0) {
            float inv = dc ? 1.0f / (float)dc : 0.0f;
            uint2 p;
            p.x = pack2(a0 * inv, a1 * inv);
            p.y = pack2(a2 * inv, a3 * inv);
            *(uint2*)&A_sh[lrow * A_STRIDE + 64 + 4 * f] = p;
        }
    }
    __syncthreads();

    // MFMA: wave w -> m-rows 16*(w&3), n-tiles {2*(w>>2), 2*(w>>2)+1}
    int wm   = w & 3;
    int ng   = (w >> 2) * 2;
    int quad = lane >> 4;
    int l15  = lane & 15;

    f32x4 accr[2] = {{0.f,0.f,0.f,0.f},{0.f,0.f,0.f,0.f}};

    #pragma unroll
    for (int k0 = 0; k0 < 128; k0 += 32) {
        short8 a = *(const short8*)&A_sh[(16 * wm + l15) * A_STRIDE + k0 + quad * 8];
        #pragma unroll
        for (int t = 0; t < 2; ++t) {
            short8 b = *(const short8*)&B_sh[(16 * (ng + t) + l15) * A_STRIDE + k0 + quad * 8];
            accr[t] = __builtin_amdgcn_mfma_f32_16x16x32_bf16(a, b, accr[t], 0, 0, 0);
        }
    }

    #pragma unroll
    for (int t = 0; t < 2; ++t) {
        int col = (ng + t) * 16 + l15;
        float bs = b_self[col];
        float bm = b_msg[col];
        #pragma unroll
        for (int r = 0; r < 4; ++r) {
            int lrow = 16 * wm + quad * 4 + r;
            int grow = r0 + lrow;
            if (grow < N_NODES) {
                float vv = accr[t][r] + bs + (cnt_sh[lrow] > 0u ? bm : 0.0f);
                out[grow * D + col] = vv;
            }
        }
    }
}

// ---------------------------------------------------------------------------
extern "C" void kernel_launch(void* const* d_in, const int* in_sizes, int n_in,
                              void* d_out, int out_size, void* d_ws, size_t ws_size,
                              hipStream_t stream) {
    const float* x      = (const float*)d_in[0];
    const int*   edges  = (const int*)  d_in[1];
    const float* W_msg  = (const float*)d_in[2];
    const float* b_msg  = (const float*)d_in[3];
    const float* W_self = (const float*)d_in[4];
    const float* b_self = (const float*)d_in[5];
    float*       out    = (float*)d_out;

    // workspace layout (bytes), total ~10.5 MB
    char* ws = (char*)d_ws;
    unsigned*       cursor      = (unsigned*)(ws + 0);             // NB u32 (counts)
    unsigned short* B_packed    = (unsigned short*)(ws + 4096);    // 16 KB
    unsigned*       bucket_data = (unsigned*)(ws + 20480);         // ~4 MB
    unsigned short* x_bf16      = (unsigned short*)(ws + 4030464); // 6.4 MB

    hipMemsetAsync(cursor, 0, NB * sizeof(unsigned), stream);      // 3 KB

    k_bin_place<<<BIN_BLOCKS, 512, 0, stream>>>(x, x_bf16, W_msg, W_self,
                                                B_packed, edges, cursor, bucket_data);
    k_fused<<<NB, 512, 0, stream>>>(x_bf16, B_packed, b_msg, b_self,
                                    cursor, bucket_data, out);
}

// Round 12
// 112.886 us; speedup vs baseline: 1.9575x; 1.0311x over previous
//
#include <hip/hip_runtime.h>

constexpr int N_NODES = 50000;
constexpr int N_EDGES = 800000;
constexpr int D = 64;
constexpr int NB = (N_NODES + 63) / 64;      // 782 buckets of 64 dst nodes
constexpr int BUCKET_CAP = 1536;             // count (<=~1200) + 64*3 pad headroom
constexpr unsigned ZERO_ROW = 50000u;        // appended all-zero x row (dummy src)

typedef __attribute__((ext_vector_type(8))) short short8;
typedef __attribute__((ext_vector_type(4))) float f32x4;

static __device__ inline unsigned short f2bf(float f) {
    unsigned u = __float_as_uint(f);
    unsigned r = (u + 0x7FFFu + ((u >> 16) & 1u)) >> 16;   // RNE
    return (unsigned short)r;
}
static __device__ inline unsigned pack2(float lo, float hi) {
    return (unsigned)f2bf(lo) | ((unsigned)f2bf(hi) << 16);
}
static __device__ inline float bf2f(unsigned short b) {
    return __uint_as_float((unsigned)b << 16);
}

// ---------------------------------------------------------------------------
// 1) merged prep + binning (round-11 structure). 256 blocks x 512.
//    Adds: block 1 zeroes the dummy x row (ZERO_ROW).
// ---------------------------------------------------------------------------
constexpr int BIN_BLOCKS = 256;
constexpr int EDGES_PER_BIN_BLOCK = (N_EDGES + BIN_BLOCKS - 1) / BIN_BLOCKS;  // 3125

__global__ __launch_bounds__(512) void k_bin_place(
    const float* __restrict__ x, unsigned short* __restrict__ xb,
    const float* __restrict__ W_msg, const float* __restrict__ W_self,
    unsigned short* __restrict__ B_packed,
    const int* __restrict__ edge_index,
    unsigned* __restrict__ g_cursor, unsigned* __restrict__ bucket_data)
{
    __shared__ unsigned ent_sh[EDGES_PER_BIN_BLOCK];   // 12.5 KB
    __shared__ unsigned lcount[NB];
    __shared__ unsigned lbase[NB];

    int tid = threadIdx.x;

    for (int b = tid; b < NB; b += 512) lcount[b] = 0u;

    // x convert, striped across the whole grid
    int gid = blockIdx.x * 512 + tid;
    for (int t = gid; t < N_NODES * D / 4; t += BIN_BLOCKS * 512) {
        float4 v = ((const float4*)x)[t];
        uint2 p;
        p.x = pack2(v.x, v.y);
        p.y = pack2(v.z, v.w);
        ((uint2*)xb)[t] = p;
    }
    if (blockIdx.x == 0) {
        for (int idx = tid; idx < 64 * 128; idx += 512) {
            int n = idx >> 7;
            int k = idx & 127;
            float v = (k < 64) ? W_self[n * 64 + k] : W_msg[n * 64 + (k - 64)];
            B_packed[idx] = f2bf(v);
        }
    } else if (blockIdx.x == 1) {
        if (tid < 8)   // zero the dummy row: 64 u16 = 8 x uint4
            *(uint4*)&xb[ZERO_ROW * D + tid * 8] = make_uint4(0u, 0u, 0u, 0u);
    }

    int e0 = blockIdx.x * EDGES_PER_BIN_BLOCK;
    int e1 = min(e0 + EDGES_PER_BIN_BLOCK, N_EDGES);
    int ne = e1 - e0;
    __syncthreads();

    // pass 1: read global once, cache in LDS, count buckets
    for (int e = e0 + tid; e < e1; e += 512) {
        int dst = edge_index[N_EDGES + e];
        int src = edge_index[e];
        ent_sh[e - e0] = ((unsigned)src << 16) | (unsigned)dst;
        atomicAdd(&lcount[dst >> 6], 1u);
    }
    __syncthreads();

    for (int b = tid; b < NB; b += 512) {
        unsigned c = lcount[b];
        lbase[b] = c ? ((unsigned)b * BUCKET_CAP + atomicAdd(&g_cursor[b], c)) : 0u;
    }
    __syncthreads();
    for (int b = tid; b < NB; b += 512) lcount[b] = 0u;
    __syncthreads();

    // pass 2: scatter from LDS
    for (int i = tid; i < ne; i += 512) {
        unsigned ent = ent_sh[i];
        unsigned dst = ent & 0xFFFFu;
        unsigned b   = dst >> 6;
        unsigned off = atomicAdd(&lcount[b], 1u);
        bucket_data[lbase[b] + off] = (ent >> 16) | ((dst & 63u) << 16);
    }
}

// ---------------------------------------------------------------------------
// 2) fused: counting-sort by dst (segments padded to x4 with dummy srcs) ->
//    quarter-wave-per-NODE gather (16 loads in flight/wave, no shfl reduce,
//    no bounds checks) -> bf16 MFMA GEMM.
// ---------------------------------------------------------------------------
constexpr int A_STRIDE = 136;   // u16 units; 272B row stride (16B-divisible)

__global__ __launch_bounds__(512) void k_fused(
    const unsigned short* __restrict__ x_bf16,
    const unsigned short* __restrict__ B_packed,
    const float* __restrict__ b_msg, const float* __restrict__ b_self,
    const unsigned* __restrict__ cursor,
    const unsigned* __restrict__ bucket_data,
    float* __restrict__ out)
{
    __shared__ __align__(16) unsigned short A_sh[64 * A_STRIDE];   // 17408 B
    __shared__ __align__(16) unsigned short B_sh[64 * A_STRIDE];   // 17408 B
    __shared__ unsigned short sorted_sh[BUCKET_CAP];               // 3072 B
    __shared__ unsigned cnt_sh[64];      // true counts
    __shared__ unsigned poff_sh[64];     // padded exclusive offsets
    __shared__ unsigned woff_sh[64];     // scatter cursors

    int tid  = threadIdx.x;
    int w    = tid >> 6;       // wave 0..7
    int lane = tid & 63;
    int r0   = blockIdx.x * 64;

    unsigned start = (unsigned)blockIdx.x * BUCKET_CAP;
    unsigned end   = start + cursor[blockIdx.x];     // cursor = count

    if (tid < 64) cnt_sh[tid] = 0u;
    // stage A x-rows (k<64): 8x 16B chunks per row
    for (int idx = tid; idx < 64 * 8; idx += 512) {
        int row = idx >> 3;
        int c   = idx & 7;
        int g   = r0 + row;
        uint4 v = make_uint4(0u, 0u, 0u, 0u);
        if (g < N_NODES) v = *(const uint4*)&x_bf16[g * D + c * 8];
        *(uint4*)&A_sh[row * A_STRIDE + c * 8] = v;
    }
    // stage B: 16x 16B chunks per row
    for (int idx = tid; idx < 64 * 16; idx += 512) {
        int n = idx >> 4;
        int c = idx & 15;
        uint4 v = *(const uint4*)&B_packed[n * 128 + c * 8];
        *(uint4*)&B_sh[n * A_STRIDE + c * 8] = v;
    }
    // prefill sorted list with dummy srcs (covers padding gaps)
    for (int i = tid; i < BUCKET_CAP; i += 512)
        sorted_sh[i] = (unsigned short)ZERO_ROW;
    __syncthreads();

    // count by dst-low
    for (unsigned i = start + tid; i < end; i += 512u)
        atomicAdd(&cnt_sh[bucket_data[i] >> 16], 1u);
    __syncthreads();

    // padded exclusive scan (wave 0)
    if (tid < 64) {
        unsigned c  = cnt_sh[tid];
        unsigned pc = (c + 3u) & ~3u;
        unsigned xsum = pc;
        #pragma unroll
        for (int s = 1; s < 64; s <<= 1) {
            unsigned v = (unsigned)__shfl_up((int)xsum, s);
            if (lane >= s) xsum += v;
        }
        poff_sh[tid] = xsum - pc;
        woff_sh[tid] = xsum - pc;
    }
    __syncthreads();

    // scatter srcs into dst-ordered padded segments
    for (unsigned i = start + tid; i < end; i += 512u) {
        unsigned e = bucket_data[i];
        unsigned slot = atomicAdd(&woff_sh[e >> 16], 1u);
        sorted_sh[slot] = (unsigned short)(e & 0xFFFFu);
    }
    __syncthreads();

    // --- gather: quarter-wave per node; wave w covers nodes w*8..w*8+7
    //     in 2 passes of 4 parallel nodes (Q). 16 lanes x ushort4 = full row.
    int Q = lane >> 4;
    int f = lane & 15;

    #pragma unroll
    for (int pass = 0; pass < 2; ++pass) {
        int lrow = w * 8 + pass * 4 + Q;
        unsigned s0 = poff_sh[lrow];
        unsigned dc = cnt_sh[lrow];
        unsigned pc = (dc + 3u) & ~3u;

        float a0 = 0.f, a1 = 0.f, a2 = 0.f, a3 = 0.f;
        for (unsigned j = 0; j < pc; j += 4u) {
            ushort4 rv[4];
            #pragma unroll
            for (int u = 0; u < 4; ++u) {
                unsigned src = (unsigned)sorted_sh[s0 + j + u];
                rv[u] = *(const ushort4*)&x_bf16[(src << 6) + 4u * (unsigned)f];
            }
            #pragma unroll
            for (int u = 0; u < 4; ++u) {
                a0 += bf2f(rv[u].x); a1 += bf2f(rv[u].y);
                a2 += bf2f(rv[u].z); a3 += bf2f(rv[u].w);
            }
        }
        float inv = dc ? 1.0f / (float)dc : 0.0f;
        uint2 p;
        p.x = pack2(a0 * inv, a1 * inv);
        p.y = pack2(a2 * inv, a3 * inv);
        *(uint2*)&A_sh[lrow * A_STRIDE + 64 + 4 * f] = p;
    }
    __syncthreads();

    // MFMA: wave w -> m-rows 16*(w&3), n-tiles {2*(w>>2), 2*(w>>2)+1}
    int wm   = w & 3;
    int ng   = (w >> 2) * 2;
    int quad = lane >> 4;
    int l15  = lane & 15;

    f32x4 accr[2] = {{0.f,0.f,0.f,0.f},{0.f,0.f,0.f,0.f}};

    #pragma unroll
    for (int k0 = 0; k0 < 128; k0 += 32) {
        short8 a = *(const short8*)&A_sh[(16 * wm + l15) * A_STRIDE + k0 + quad * 8];
        #pragma unroll
        for (int t = 0; t < 2; ++t) {
            short8 b = *(const short8*)&B_sh[(16 * (ng + t) + l15) * A_STRIDE + k0 + quad * 8];
            accr[t] = __builtin_amdgcn_mfma_f32_16x16x32_bf16(a, b, accr[t], 0, 0, 0);
        }
    }

    #pragma unroll
    for (int t = 0; t < 2; ++t) {
        int col = (ng + t) * 16 + l15;
        float bs = b_self[col];
        float bm = b_msg[col];
        #pragma unroll
        for (int r = 0; r < 4; ++r) {
            int lrow = 16 * wm + quad * 4 + r;
            int grow = r0 + lrow;
            if (grow < N_NODES) {
                float vv = accr[t][r] + bs + (cnt_sh[lrow] > 0u ? bm : 0.0f);
                out[grow * D + col] = vv;
            }
        }
    }
}

// ---------------------------------------------------------------------------
extern "C" void kernel_launch(void* const* d_in, const int* in_sizes, int n_in,
                              void* d_out, int out_size, void* d_ws, size_t ws_size,
                              hipStream_t stream) {
    const float* x      = (const float*)d_in[0];
    const int*   edges  = (const int*)  d_in[1];
    const float* W_msg  = (const float*)d_in[2];
    const float* b_msg  = (const float*)d_in[3];
    const float* W_self = (const float*)d_in[4];
    const float* b_self = (const float*)d_in[5];
    float*       out    = (float*)d_out;

    // workspace layout (bytes), total ~11.3 MB
    char* ws = (char*)d_ws;
    unsigned*       cursor      = (unsigned*)(ws + 0);             // NB u32 (counts)
    unsigned short* B_packed    = (unsigned short*)(ws + 4096);    // 16 KB
    unsigned*       bucket_data = (unsigned*)(ws + 20480);         // 782*1536*4 = 4,804,608 B
    unsigned short* x_bf16      = (unsigned short*)(ws + 20480 + (size_t)NB * BUCKET_CAP * 4);
                                                                   // 50001 rows x 128 B

    hipMemsetAsync(cursor, 0, NB * sizeof(unsigned), stream);      // 3 KB

    k_bin_place<<<BIN_BLOCKS, 512, 0, stream>>>(x, x_bf16, W_msg, W_self,
                                                B_packed, edges, cursor, bucket_data);
    k_fused<<<NB, 512, 0, stream>>>(x_bf16, B_packed, b_msg, b_self,
                                    cursor, bucket_data, out);
}